// Round 11
// baseline (49.213 us; speedup 1.0000x reference)
//
#include <hip/hip_runtime.h>

#define TWO_N 8192
#define HALF_N 4096
#define DIM 256
#define PANEL_BYTES 8192                     // 16 rows x 256 el x 2B

#define NBLK 64                              // 8192 / 128 row-blocks
#define ROWS_PER_BLOCK 128
#define CH_COLS 32
#define CHUNK_BYTES (CH_COLS * DIM * 2)      // 16 KB (2 panels)
#define NWG 576                              // 64 x 9 tile-pair blocks
#define WG_PER_XCD 72                        // 576 / 8, exact -> bijective

#define KAPPA 14.426950408889634f            // 10*log2(e)
#define SQRT_KAPPA 3.798282565f
#define LN2 0.6931471805599453f

typedef __attribute__((ext_vector_type(8))) short bf16x8;
typedef __attribute__((ext_vector_type(8))) unsigned short ushort8;
typedef __attribute__((ext_vector_type(4))) float f32x4;

__device__ __forceinline__ float bf2f(unsigned short u) {
  return __uint_as_float(((unsigned int)u) << 16);
}
__device__ __forceinline__ unsigned short f2bf(float f) {
  unsigned int u = __float_as_uint(f);
  return (unsigned short)((u + 0x7FFFu + ((u >> 16) & 1u)) >> 16);
}
__device__ __forceinline__ void async_copy16(void* lds_dst, const void* g_src) {
  __builtin_amdgcn_global_load_lds(
      (const __attribute__((address_space(1))) unsigned int*)g_src,
      (__attribute__((address_space(3))) unsigned int*)lds_dst, 16, 0, 0);
}

// rnB layout: panel p (16 rows), byte offset p*8192 + kk*1024 + (g*16 + r)*16
// holds row (p*16+r), k-elements kk*32 + g*8 .. +8, as bf16 scaled by
// SQRT_KAPPA. So any MFMA dot of two stored rows = KAPPA * cos-sim.

// K1: normalize 16 rows (one panel) per block; write fragment-major rnB
// scaled by SQRT_KAPPA. Also zero rowsum and out.
__global__ __launch_bounds__(256) void k_norm(const float* __restrict__ zi,
                                              const float* __restrict__ zj,
                                              unsigned short* __restrict__ rnB,
                                              float* __restrict__ rowsum,
                                              float* __restrict__ out) {
  int p = blockIdx.x;
  int wave = threadIdx.x >> 6, lane = threadIdx.x & 63;
  int rp = wave * 4 + (lane >> 4);           // row within panel
  int row = p * 16 + rp;
  int kslot = lane & 15;                     // 16 elems per thread
  int k0 = kslot * 16;
  if (threadIdx.x < 16) rowsum[p * 16 + threadIdx.x] = 0.0f;
  if (p == 0 && threadIdx.x == 0) out[0] = 0.0f;

  const float* src = (row < HALF_N) ? (zi + (size_t)row * DIM)
                                    : (zj + (size_t)(row - HALF_N) * DIM);
  float4 v[4];
  #pragma unroll
  for (int q = 0; q < 4; ++q)
    v[q] = *reinterpret_cast<const float4*>(src + k0 + q * 4);
  float ss = 0.0f;
  #pragma unroll
  for (int q = 0; q < 4; ++q)
    ss += v[q].x * v[q].x + v[q].y * v[q].y + v[q].z * v[q].z + v[q].w * v[q].w;
  #pragma unroll
  for (int m = 1; m <= 8; m <<= 1) ss += __shfl_xor(ss, m, 64);
  float r = rsqrtf(ss) * SQRT_KAPPA;

  ushort8 u0, u1;
  #pragma unroll
  for (int q = 0; q < 2; ++q) {
    u0[q * 4 + 0] = f2bf(v[q].x * r); u0[q * 4 + 1] = f2bf(v[q].y * r);
    u0[q * 4 + 2] = f2bf(v[q].z * r); u0[q * 4 + 3] = f2bf(v[q].w * r);
    u1[q * 4 + 0] = f2bf(v[q + 2].x * r); u1[q * 4 + 1] = f2bf(v[q + 2].y * r);
    u1[q * 4 + 2] = f2bf(v[q + 2].z * r); u1[q * 4 + 3] = f2bf(v[q + 2].w * r);
  }
  int kk = kslot >> 1;
  int g = (kslot & 1) * 2;
  char* pb = (char*)rnB + (size_t)p * PANEL_BYTES + kk * 1024;
  *reinterpret_cast<ushort8*>(pb + (g * 16 + rp) * 16) = u0;
  *reinterpret_cast<ushort8*>(pb + ((g + 1) * 16 + rp) * 16) = u1;
}

// K2: symmetric Gram rowsums, 128-row block x 512-col span, tri-buffered LDS
// with counted vmcnt(4). XCD-chunked bijective swizzle (T1/m204): each XCD
// gets 72 consecutive (s,bi) ids -> co-resident blocks share one s-span and
// each B-tile is re-read by ~4 same-XCD blocks (L2 hits, not L3 refetch).
// Pairs {bi, bj = bi+dd mod 64}: span s covers dd = 4s..4s+3 (s=0 includes
// the diagonal tile), s=8 is the single dd=32 tile, deduped by bi<32.
__global__ __launch_bounds__(256, 3) void k_sim(const unsigned short* __restrict__ rnB,
                                                float* __restrict__ rowsum) {
  __shared__ alignas(16) char lds[3][CHUNK_BYTES];
  int wg = blockIdx.x;
  int sw = (wg & 7) * WG_PER_XCD + (wg >> 3);   // bijective XCD chunking
  int bi = sw & (NBLK - 1);
  int s = sw >> 6;
  if (s == 8 && bi >= 32) return;            // dedupe dd=32 involution
  const int NT = (s == 8) ? 4 : 16;          // chunks of 32 cols
  int dd0 = s * 4;

  int wave = threadIdx.x >> 6, lane = threadIdx.x & 63;
  int lrow = lane & 15, kgrp = lane >> 4;
  int r0 = bi * ROWS_PER_BLOCK + wave * 32;
  const char* base = (const char*)rnB;

  // A: 2 strips (32 rows) per wave, linear loads from fragment-major panels.
  bf16x8 a[2][8];
  #pragma unroll
  for (int st = 0; st < 2; ++st) {
    const char* pa = base + (size_t)(bi * 8 + wave * 2 + st) * PANEL_BYTES + lane * 16;
    #pragma unroll
    for (int kk = 0; kk < 8; ++kk)
      a[st][kk] = *reinterpret_cast<const bf16x8*>(pa + kk * 1024);
  }

  float se[2][4];
  #pragma unroll
  for (int st = 0; st < 2; ++st)
    #pragma unroll
    for (int g = 0; g < 4; ++g) se[st][g] = 0.0f;

  // stage chunk ch (32 cols of tile ch>>2) into lds[buf]; 4 KB per wave,
  // perfectly linear (LDS image == global fragment-major bytes).
  auto stage = [&](int buf, int ch) {
    int bj = (bi + dd0 + (ch >> 2)) & (NBLK - 1);
    const char* gp = base + ((size_t)bj * 8 + (size_t)(ch & 3) * 2) * PANEL_BYTES +
                     wave * 4096 + lane * 16;
    char* dst = &lds[buf][wave * 4096];
    #pragma unroll
    for (int q = 0; q < 4; ++q)
      async_copy16(dst + q * 1024, gp + q * 1024);
  };

  stage(0, 0);
  stage(1, 1);
  asm volatile("s_waitcnt vmcnt(4)" ::: "memory");   // chunk 0 landed
  __builtin_amdgcn_s_barrier();

  for (int ch = 0; ch < NT; ++ch) {
    if (ch + 2 < NT) stage((ch + 2) % 3, ch + 2);
    const char* lb = lds[ch % 3] + lane * 16;
    int bjc = (bi + dd0 + (ch >> 2)) & (NBLK - 1);
    bool diag = (dd0 + (ch >> 2)) == 0;
    #pragma unroll
    for (int h = 0; h < 2; ++h) {
      f32x4 acc0 = {-KAPPA, -KAPPA, -KAPPA, -KAPPA};
      f32x4 acc1 = {-KAPPA, -KAPPA, -KAPPA, -KAPPA};
      __builtin_amdgcn_s_setprio(1);
      #pragma unroll
      for (int kk = 0; kk < 8; ++kk) {
        bf16x8 b = *reinterpret_cast<const bf16x8*>(lb + h * 8192 + kk * 1024);
        acc0 = __builtin_amdgcn_mfma_f32_16x16x32_bf16(a[0][kk], b, acc0, 0, 0, 0);
        acc1 = __builtin_amdgcn_mfma_f32_16x16x32_bf16(a[1][kk], b, acc1, 0, 0, 0);
      }
      __builtin_amdgcn_s_setprio(0);
      float scc = 0.0f;
      #pragma unroll
      for (int g = 0; g < 4; ++g) {
        float e0 = __builtin_amdgcn_exp2f(acc0[g]);
        float e1 = __builtin_amdgcn_exp2f(acc1[g]);
        se[0][g] += e0;
        se[1][g] += e1;
        scc += e0 + e1;
      }
      if (!diag) {
        // column sums of this 16-col panel -> rows of bjc (transposed tile)
        scc += __shfl_xor(scc, 16, 64);
        scc += __shfl_xor(scc, 32, 64);
        if (lane < 16)
          atomicAdd(&rowsum[bjc * ROWS_PER_BLOCK + (ch & 3) * CH_COLS + h * 16 + lane], scc);
      }
    }
    if (ch + 1 < NT) {
      // counted drain: next chunk landed; keep the one after in flight.
      if (ch + 2 < NT)
        asm volatile("s_waitcnt vmcnt(4)" ::: "memory");
      else
        asm volatile("s_waitcnt vmcnt(0)" ::: "memory");
      __builtin_amdgcn_s_barrier();
    }
  }

  // row sums: reduce over 16 column-lanes, one atomic per row
  #pragma unroll
  for (int st = 0; st < 2; ++st) {
    #pragma unroll
    for (int g = 0; g < 4; ++g) {
      float v = se[st][g];
      #pragma unroll
      for (int m = 1; m <= 8; m <<= 1) v += __shfl_xor(v, m, 64);
      if (lrow == 0) atomicAdd(&rowsum[r0 + 16 * st + kgrp * 4 + g], v);
    }
  }
}

// K3: per pair (i, j=i+N): subtract self term, lse - pos for both rows.
// Stored dots are KAPPA-scaled: pos = LN2*dp, self = exp2(sf - KAPPA).
__global__ __launch_bounds__(256) void k_rowred(const unsigned short* __restrict__ rnB,
                                               const float* __restrict__ rowsum,
                                               float* __restrict__ out) {
  __shared__ float ls[4];
  int wave = threadIdx.x >> 6, lane = threadIdx.x & 63;
  int q = lane & 31;
  float local = 0.0f;
  #pragma unroll
  for (int t = 0; t < 8; ++t) {
    int i = blockIdx.x * 32 + wave * 8 + t;              // pair 0..4095
    int row = (lane >> 5) ? i + HALF_N : i;
    int panel = row >> 4, r = row & 15;
    const char* addr = (const char*)rnB + (size_t)panel * PANEL_BYTES +
                       (q >> 2) * 1024 + ((q & 3) * 16 + r) * 16;
    ushort8 own = *reinterpret_cast<const ushort8*>(addr);
    int4 ow = *reinterpret_cast<int4*>(&own);
    int4 pw;
    pw.x = __shfl_xor(ow.x, 32, 64); pw.y = __shfl_xor(ow.y, 32, 64);
    pw.z = __shfl_xor(ow.z, 32, 64); pw.w = __shfl_xor(ow.w, 32, 64);
    ushort8 part = *reinterpret_cast<ushort8*>(&pw);
    float dp = 0.0f, sf = 0.0f;
    #pragma unroll
    for (int e = 0; e < 8; ++e) {
      float av = bf2f(own[e]), bv = bf2f(part[e]);
      dp += av * bv;
      sf += av * av;
    }
    #pragma unroll
    for (int m = 1; m <= 16; m <<= 1) {
      dp += __shfl_xor(dp, m, 64);
      sf += __shfl_xor(sf, m, 64);
    }
    if (q == 0) {                     // lanes 0 (row i) and 32 (row j)
      float self = __builtin_amdgcn_exp2f(sf - KAPPA);
      float rs = rowsum[row] - self;
      float lse = 10.0f + LN2 * __builtin_amdgcn_logf(rs);  // logf = log2
      local += lse - LN2 * dp;        // pos = 10*d = LN2 * (KAPPA*d)
    }
  }
  local += __shfl_xor(local, 32, 64);
  if (lane == 0) ls[wave] = local;
  __syncthreads();
  if (threadIdx.x == 0)
    atomicAdd(out, (ls[0] + ls[1] + ls[2] + ls[3]) * (1.0f / TWO_N));
}

extern "C" void kernel_launch(void* const* d_in, const int* in_sizes, int n_in,
                              void* d_out, int out_size, void* d_ws, size_t ws_size,
                              hipStream_t stream) {
  const float* zi = (const float*)d_in[0];
  const float* zj = (const float*)d_in[1];
  unsigned short* rnB = (unsigned short*)d_ws;                      // 4 MB
  float* rowsum = (float*)((char*)d_ws + (size_t)TWO_N * DIM * 2);  // 32 KB
  float* out = (float*)d_out;

  hipLaunchKernelGGL(k_norm, dim3(TWO_N / 16), dim3(256), 0, stream, zi, zj, rnB, rowsum, out);
  hipLaunchKernelGGL(k_sim, dim3(NWG), dim3(256), 0, stream, rnB, rowsum);
  hipLaunchKernelGGL(k_rowred, dim3(HALF_N / 32), dim3(256), 0, stream, rnB, rowsum, out);
}

// Round 12
// 46.557 us; speedup vs baseline: 1.0571x; 1.0571x over previous
//
#include <hip/hip_runtime.h>

#define TWO_N 8192
#define HALF_N 4096
#define DIM 256
#define PANEL_BYTES 8192                     // 16 rows x 256 el x 2B

#define NSB 32                               // 8192 / 256 row-superblocks
#define SB_ROWS 256
#define CH_COLS 32
#define CHUNK_BYTES (CH_COLS * DIM * 2)      // 16 KB (2 panels)
#define NT 8                                 // 256 cols / 32

#define KAPPA 14.426950408889634f            // 10*log2(e)
#define SQRT_KAPPA 3.798282565f
#define LN2 0.6931471805599453f

typedef __attribute__((ext_vector_type(8))) short bf16x8;
typedef __attribute__((ext_vector_type(8))) unsigned short ushort8;
typedef __attribute__((ext_vector_type(4))) float f32x4;

__device__ __forceinline__ float bf2f(unsigned short u) {
  return __uint_as_float(((unsigned int)u) << 16);
}
__device__ __forceinline__ unsigned short f2bf(float f) {
  unsigned int u = __float_as_uint(f);
  return (unsigned short)((u + 0x7FFFu + ((u >> 16) & 1u)) >> 16);
}
__device__ __forceinline__ void async_copy16(void* lds_dst, const void* g_src) {
  __builtin_amdgcn_global_load_lds(
      (const __attribute__((address_space(1))) unsigned int*)g_src,
      (__attribute__((address_space(3))) unsigned int*)lds_dst, 16, 0, 0);
}

// rnB layout: panel p (16 rows), byte offset p*8192 + kk*1024 + (g*16 + r)*16
// holds row (p*16+r), k-elements kk*32 + g*8 .. +8, as bf16 scaled by
// SQRT_KAPPA. So any MFMA dot of two stored rows = KAPPA * cos-sim.

// K1: normalize 16 rows (one panel) per block; write fragment-major rnB
// scaled by SQRT_KAPPA. Also zero rowsum and out.
__global__ __launch_bounds__(256) void k_norm(const float* __restrict__ zi,
                                              const float* __restrict__ zj,
                                              unsigned short* __restrict__ rnB,
                                              float* __restrict__ rowsum,
                                              float* __restrict__ out) {
  int p = blockIdx.x;
  int wave = threadIdx.x >> 6, lane = threadIdx.x & 63;
  int rp = wave * 4 + (lane >> 4);           // row within panel
  int row = p * 16 + rp;
  int kslot = lane & 15;                     // 16 elems per thread
  int k0 = kslot * 16;
  if (threadIdx.x < 16) rowsum[p * 16 + threadIdx.x] = 0.0f;
  if (p == 0 && threadIdx.x == 0) out[0] = 0.0f;

  const float* src = (row < HALF_N) ? (zi + (size_t)row * DIM)
                                    : (zj + (size_t)(row - HALF_N) * DIM);
  float4 v[4];
  #pragma unroll
  for (int q = 0; q < 4; ++q)
    v[q] = *reinterpret_cast<const float4*>(src + k0 + q * 4);
  float ss = 0.0f;
  #pragma unroll
  for (int q = 0; q < 4; ++q)
    ss += v[q].x * v[q].x + v[q].y * v[q].y + v[q].z * v[q].z + v[q].w * v[q].w;
  #pragma unroll
  for (int m = 1; m <= 8; m <<= 1) ss += __shfl_xor(ss, m, 64);
  float r = rsqrtf(ss) * SQRT_KAPPA;

  ushort8 u0, u1;
  #pragma unroll
  for (int q = 0; q < 2; ++q) {
    u0[q * 4 + 0] = f2bf(v[q].x * r); u0[q * 4 + 1] = f2bf(v[q].y * r);
    u0[q * 4 + 2] = f2bf(v[q].z * r); u0[q * 4 + 3] = f2bf(v[q].w * r);
    u1[q * 4 + 0] = f2bf(v[q + 2].x * r); u1[q * 4 + 1] = f2bf(v[q + 2].y * r);
    u1[q * 4 + 2] = f2bf(v[q + 2].z * r); u1[q * 4 + 3] = f2bf(v[q + 2].w * r);
  }
  int kk = kslot >> 1;
  int g = (kslot & 1) * 2;
  char* pb = (char*)rnB + (size_t)p * PANEL_BYTES + kk * 1024;
  *reinterpret_cast<ushort8*>(pb + (g * 16 + rp) * 16) = u0;
  *reinterpret_cast<ushort8*>(pb + ((g + 1) * 16 + rp) * 16) = u1;
}

// K2: symmetric Gram rowsums. 256-row superblock (4 waves x 64 rows, 4 A
// strips resident = 128 VGPR) x 256-col tile; pairs {p, q=p+d mod 32},
// d=0..16, d=16 deduped. 64 FLOP per LDS-byte (4 MFMAs per B fragment) --
// LDS traffic 270 MB total, below the MFMA floor. Tri-buffered LDS staging
// with counted vmcnt(4); rolled chunk loop (no unroll -> no spill).
// Row-exp-sums -> registers -> atomics; col-sums -> global atomics (d>0).
__global__ __launch_bounds__(256, 2) void k_sim(const unsigned short* __restrict__ rnB,
                                                float* __restrict__ rowsum) {
  __shared__ alignas(16) char lds[3][CHUNK_BYTES];
  int p = blockIdx.x;                        // row superblock 0..31
  int d = blockIdx.y;                        // ring distance 0..16
  if (d == 16 && p >= 16) return;            // dedupe involutive offset
  int q = (p + d) & (NSB - 1);
  bool diag = (d == 0);

  int wave = threadIdx.x >> 6, lane = threadIdx.x & 63;
  int lrow = lane & 15, kgrp = lane >> 4;
  const char* base = (const char*)rnB;

  // A: 4 strips (64 rows) per wave, linear loads from fragment-major panels.
  bf16x8 a[4][8];
  #pragma unroll
  for (int st = 0; st < 4; ++st) {
    const char* pa = base + (size_t)(p * 16 + wave * 4 + st) * PANEL_BYTES + lane * 16;
    #pragma unroll
    for (int kk = 0; kk < 8; ++kk)
      a[st][kk] = *reinterpret_cast<const bf16x8*>(pa + kk * 1024);
  }

  float se[4][4];
  #pragma unroll
  for (int st = 0; st < 4; ++st)
    #pragma unroll
    for (int g = 0; g < 4; ++g) se[st][g] = 0.0f;

  // stage chunk ch (32 cols of tile q) into lds[buf]; 4 KB per wave, linear.
  auto stage = [&](int buf, int ch) {
    const char* gp = base + (size_t)(q * 16 + ch * 2) * PANEL_BYTES +
                     wave * 4096 + lane * 16;
    char* dst = &lds[buf][wave * 4096];
    #pragma unroll
    for (int t = 0; t < 4; ++t)
      async_copy16(dst + t * 1024, gp + t * 1024);
  };

  stage(0, 0);
  stage(1, 1);
  asm volatile("s_waitcnt vmcnt(4)" ::: "memory");   // chunk 0 landed
  __builtin_amdgcn_s_barrier();

  int cur = 0, stg = 2;
  for (int ch = 0; ch < NT; ++ch) {
    if (ch + 2 < NT) stage(stg, ch + 2);
    const char* lb = lds[cur] + lane * 16;
    #pragma unroll
    for (int h = 0; h < 2; ++h) {
      f32x4 acc[4];
      #pragma unroll
      for (int st = 0; st < 4; ++st)
        acc[st] = (f32x4){-KAPPA, -KAPPA, -KAPPA, -KAPPA};
      __builtin_amdgcn_s_setprio(1);
      #pragma unroll
      for (int kk = 0; kk < 8; ++kk) {
        bf16x8 b = *reinterpret_cast<const bf16x8*>(lb + h * 8192 + kk * 1024);
        #pragma unroll
        for (int st = 0; st < 4; ++st)
          acc[st] = __builtin_amdgcn_mfma_f32_16x16x32_bf16(a[st][kk], b, acc[st], 0, 0, 0);
      }
      __builtin_amdgcn_s_setprio(0);
      float scc = 0.0f;
      #pragma unroll
      for (int st = 0; st < 4; ++st) {
        #pragma unroll
        for (int g = 0; g < 4; ++g) {
          float e = __builtin_amdgcn_exp2f(acc[st][g]);
          se[st][g] += e;
          scc += e;
        }
      }
      if (!diag) {
        // column sums of this 16-col panel -> rows of q (transposed tile)
        scc += __shfl_xor(scc, 16, 64);
        scc += __shfl_xor(scc, 32, 64);
        if (lane < 16)
          atomicAdd(&rowsum[q * SB_ROWS + ch * CH_COLS + h * 16 + lane], scc);
      }
    }
    if (ch + 1 < NT) {
      // counted drain: next chunk landed; keep the one after in flight.
      if (ch + 2 < NT)
        asm volatile("s_waitcnt vmcnt(4)" ::: "memory");
      else
        asm volatile("s_waitcnt vmcnt(0)" ::: "memory");
      __builtin_amdgcn_s_barrier();
    }
    cur = (cur == 2) ? 0 : cur + 1;
    stg = (stg == 2) ? 0 : stg + 1;
  }

  // row sums: reduce over 16 column-lanes, one atomic per row
  #pragma unroll
  for (int st = 0; st < 4; ++st) {
    #pragma unroll
    for (int g = 0; g < 4; ++g) {
      float v = se[st][g];
      #pragma unroll
      for (int m = 1; m <= 8; m <<= 1) v += __shfl_xor(v, m, 64);
      if (lrow == 0)
        atomicAdd(&rowsum[p * SB_ROWS + wave * 64 + st * 16 + kgrp * 4 + g], v);
    }
  }
}

// K3: per pair (i, j=i+N): subtract self term, lse - pos for both rows.
// Stored dots are KAPPA-scaled: pos = LN2*dp, self = exp2(sf - KAPPA).
__global__ __launch_bounds__(256) void k_rowred(const unsigned short* __restrict__ rnB,
                                               const float* __restrict__ rowsum,
                                               float* __restrict__ out) {
  __shared__ float ls[4];
  int wave = threadIdx.x >> 6, lane = threadIdx.x & 63;
  int q = lane & 31;
  float local = 0.0f;
  #pragma unroll
  for (int t = 0; t < 8; ++t) {
    int i = blockIdx.x * 32 + wave * 8 + t;              // pair 0..4095
    int row = (lane >> 5) ? i + HALF_N : i;
    int panel = row >> 4, r = row & 15;
    const char* addr = (const char*)rnB + (size_t)panel * PANEL_BYTES +
                       (q >> 2) * 1024 + ((q & 3) * 16 + r) * 16;
    ushort8 own = *reinterpret_cast<const ushort8*>(addr);
    int4 ow = *reinterpret_cast<int4*>(&own);
    int4 pw;
    pw.x = __shfl_xor(ow.x, 32, 64); pw.y = __shfl_xor(ow.y, 32, 64);
    pw.z = __shfl_xor(ow.z, 32, 64); pw.w = __shfl_xor(ow.w, 32, 64);
    ushort8 part = *reinterpret_cast<ushort8*>(&pw);
    float dp = 0.0f, sf = 0.0f;
    #pragma unroll
    for (int e = 0; e < 8; ++e) {
      float av = bf2f(own[e]), bv = bf2f(part[e]);
      dp += av * bv;
      sf += av * av;
    }
    #pragma unroll
    for (int m = 1; m <= 16; m <<= 1) {
      dp += __shfl_xor(dp, m, 64);
      sf += __shfl_xor(sf, m, 64);
    }
    if (q == 0) {                     // lanes 0 (row i) and 32 (row j)
      float self = __builtin_amdgcn_exp2f(sf - KAPPA);
      float rs = rowsum[row] - self;
      float lse = 10.0f + LN2 * __builtin_amdgcn_logf(rs);  // logf = log2
      local += lse - LN2 * dp;        // pos = 10*d = LN2 * (KAPPA*d)
    }
  }
  local += __shfl_xor(local, 32, 64);
  if (lane == 0) ls[wave] = local;
  __syncthreads();
  if (threadIdx.x == 0)
    atomicAdd(out, (ls[0] + ls[1] + ls[2] + ls[3]) * (1.0f / TWO_N));
}

extern "C" void kernel_launch(void* const* d_in, const int* in_sizes, int n_in,
                              void* d_out, int out_size, void* d_ws, size_t ws_size,
                              hipStream_t stream) {
  const float* zi = (const float*)d_in[0];
  const float* zj = (const float*)d_in[1];
  unsigned short* rnB = (unsigned short*)d_ws;                      // 4 MB
  float* rowsum = (float*)((char*)d_ws + (size_t)TWO_N * DIM * 2);  // 32 KB
  float* out = (float*)d_out;

  hipLaunchKernelGGL(k_norm, dim3(TWO_N / 16), dim3(256), 0, stream, zi, zj, rnB, rowsum, out);
  hipLaunchKernelGGL(k_sim, dim3(NSB, 17), dim3(256), 0, stream, rnB, rowsum);
  hipLaunchKernelGGL(k_rowred, dim3(HALF_N / 32), dim3(256), 0, stream, rnB, rowsum, out);
}

// Round 13
// 44.115 us; speedup vs baseline: 1.1156x; 1.0554x over previous
//
#include <hip/hip_runtime.h>

#define TWO_N 8192
#define HALF_N 4096
#define DIM 256
#define PANEL_BYTES 8192                     // 16 rows x 256 el x 2B

#define NBLK 64                              // 8192 / 128 row-blocks
#define ROWS_PER_BLOCK 128
#define CH_COLS 32
#define CHUNK_BYTES (CH_COLS * DIM * 2)      // 16 KB (2 panels)

#define KAPPA 14.426950408889634f            // 10*log2(e)
#define SQRT_KAPPA 3.798282565f
#define LN2 0.6931471805599453f

typedef __attribute__((ext_vector_type(8))) short bf16x8;
typedef __attribute__((ext_vector_type(8))) unsigned short ushort8;
typedef __attribute__((ext_vector_type(4))) float f32x4;

__device__ __forceinline__ float bf2f(unsigned short u) {
  return __uint_as_float(((unsigned int)u) << 16);
}
__device__ __forceinline__ unsigned short f2bf(float f) {
  unsigned int u = __float_as_uint(f);
  return (unsigned short)((u + 0x7FFFu + ((u >> 16) & 1u)) >> 16);
}
__device__ __forceinline__ void async_copy16(void* lds_dst, const void* g_src) {
  __builtin_amdgcn_global_load_lds(
      (const __attribute__((address_space(1))) unsigned int*)g_src,
      (__attribute__((address_space(3))) unsigned int*)lds_dst, 16, 0, 0);
}

// rnB layout: panel p (16 rows), byte offset p*8192 + kk*1024 + (g*16 + r)*16
// holds row (p*16+r), k-elements kk*32 + g*8 .. +8, as bf16 scaled by
// SQRT_KAPPA. So any MFMA dot of two stored rows = KAPPA * cos-sim.

// K1: normalize 16 rows (one panel) per block; write fragment-major rnB
// scaled by SQRT_KAPPA. Also zero rowsum and out.
__global__ __launch_bounds__(256) void k_norm(const float* __restrict__ zi,
                                              const float* __restrict__ zj,
                                              unsigned short* __restrict__ rnB,
                                              float* __restrict__ rowsum,
                                              float* __restrict__ out) {
  int p = blockIdx.x;
  int wave = threadIdx.x >> 6, lane = threadIdx.x & 63;
  int rp = wave * 4 + (lane >> 4);           // row within panel
  int row = p * 16 + rp;
  int kslot = lane & 15;                     // 16 elems per thread
  int k0 = kslot * 16;
  if (threadIdx.x < 16) rowsum[p * 16 + threadIdx.x] = 0.0f;
  if (p == 0 && threadIdx.x == 0) out[0] = 0.0f;

  const float* src = (row < HALF_N) ? (zi + (size_t)row * DIM)
                                    : (zj + (size_t)(row - HALF_N) * DIM);
  float4 v[4];
  #pragma unroll
  for (int q = 0; q < 4; ++q)
    v[q] = *reinterpret_cast<const float4*>(src + k0 + q * 4);
  float ss = 0.0f;
  #pragma unroll
  for (int q = 0; q < 4; ++q)
    ss += v[q].x * v[q].x + v[q].y * v[q].y + v[q].z * v[q].z + v[q].w * v[q].w;
  #pragma unroll
  for (int m = 1; m <= 8; m <<= 1) ss += __shfl_xor(ss, m, 64);
  float r = rsqrtf(ss) * SQRT_KAPPA;

  ushort8 u0, u1;
  #pragma unroll
  for (int q = 0; q < 2; ++q) {
    u0[q * 4 + 0] = f2bf(v[q].x * r); u0[q * 4 + 1] = f2bf(v[q].y * r);
    u0[q * 4 + 2] = f2bf(v[q].z * r); u0[q * 4 + 3] = f2bf(v[q].w * r);
    u1[q * 4 + 0] = f2bf(v[q + 2].x * r); u1[q * 4 + 1] = f2bf(v[q + 2].y * r);
    u1[q * 4 + 2] = f2bf(v[q + 2].z * r); u1[q * 4 + 3] = f2bf(v[q + 2].w * r);
  }
  int kk = kslot >> 1;
  int g = (kslot & 1) * 2;
  char* pb = (char*)rnB + (size_t)p * PANEL_BYTES + kk * 1024;
  *reinterpret_cast<ushort8*>(pb + (g * 16 + rp) * 16) = u0;
  *reinterpret_cast<ushort8*>(pb + ((g + 1) * 16 + rp) * 16) = u1;
}

// K2: symmetric Gram rowsums, 128-row block x 512-col span, tri-buffered LDS
// with counted vmcnt(4). Epilogue software-pipelined: chunk ch's exp/sum runs
// behind chunk ch+1's MFMAs (separate pipes, ping-pong acc regs). Col-sums
// accumulate in LDS (DS atomics, no vmem ops in the counted window), flushed
// once at the end. Pairs {bi, bj=bi+dd mod 64}: span s covers dd=4s..4s+3
// (s=0 includes the diagonal tile), s=8 is dd=32 deduped by bi<32.
__global__ __launch_bounds__(256, 3) void k_sim(const unsigned short* __restrict__ rnB,
                                                float* __restrict__ rowsum) {
  __shared__ alignas(16) char lds[3][CHUNK_BYTES];
  __shared__ float colacc[512];
  int bi = blockIdx.x;
  int s = blockIdx.y;
  if (s == 8 && bi >= 32) return;            // dedupe dd=32 involution
  const int NT = (s == 8) ? 4 : 16;          // chunks of 32 cols
  int dd0 = s * 4;
  int diag_until = (s == 0) ? 4 : 0;         // chunks < this are the diag tile

  int wave = threadIdx.x >> 6, lane = threadIdx.x & 63;
  int lrow = lane & 15, kgrp = lane >> 4;
  int r0 = bi * ROWS_PER_BLOCK + wave * 32;
  const char* base = (const char*)rnB;

  colacc[threadIdx.x] = 0.0f;
  colacc[threadIdx.x + 256] = 0.0f;

  // A: 2 strips (32 rows) per wave, linear loads from fragment-major panels.
  bf16x8 a[2][8];
  #pragma unroll
  for (int st = 0; st < 2; ++st) {
    const char* pa = base + (size_t)(bi * 8 + wave * 2 + st) * PANEL_BYTES + lane * 16;
    #pragma unroll
    for (int kk = 0; kk < 8; ++kk)
      a[st][kk] = *reinterpret_cast<const bf16x8*>(pa + kk * 1024);
  }

  float se[2][4];
  #pragma unroll
  for (int st = 0; st < 2; ++st)
    #pragma unroll
    for (int g = 0; g < 4; ++g) se[st][g] = 0.0f;

  // stage chunk ch (32 cols of tile ch>>2) into lds[buf]; 4 KB/wave, linear.
  auto stage = [&](int buf, int ch) {
    int bj = (bi + dd0 + (ch >> 2)) & (NBLK - 1);
    const char* gp = base + ((size_t)bj * 8 + (size_t)(ch & 3) * 2) * PANEL_BYTES +
                     wave * 4096 + lane * 16;
    char* dst = &lds[buf][wave * 4096];
    #pragma unroll
    for (int q = 0; q < 4; ++q)
      async_copy16(dst + q * 1024, gp + q * 1024);
  };

  // 32 MFMAs of one chunk into 4 fresh accs (h in {0,1} halves x 2 strips).
  auto mfma_chunk = [&](int c, f32x4& o00, f32x4& o01, f32x4& o10, f32x4& o11) {
    const char* lb = lds[c % 3] + lane * 16;
    f32x4 init = {-KAPPA, -KAPPA, -KAPPA, -KAPPA};
    o00 = init; o01 = init; o10 = init; o11 = init;
    __builtin_amdgcn_s_setprio(1);
    #pragma unroll
    for (int kk = 0; kk < 8; ++kk) {
      bf16x8 b0 = *reinterpret_cast<const bf16x8*>(lb + kk * 1024);
      bf16x8 b1 = *reinterpret_cast<const bf16x8*>(lb + 8192 + kk * 1024);
      o00 = __builtin_amdgcn_mfma_f32_16x16x32_bf16(a[0][kk], b0, o00, 0, 0, 0);
      o10 = __builtin_amdgcn_mfma_f32_16x16x32_bf16(a[1][kk], b0, o10, 0, 0, 0);
      o01 = __builtin_amdgcn_mfma_f32_16x16x32_bf16(a[0][kk], b1, o01, 0, 0, 0);
      o11 = __builtin_amdgcn_mfma_f32_16x16x32_bf16(a[1][kk], b1, o11, 0, 0, 0);
    }
    __builtin_amdgcn_s_setprio(0);
  };

  // exps + row-accumulate + col-accumulate (LDS) for one finished chunk.
  auto epilogue = [&](f32x4& o00, f32x4& o01, f32x4& o10, f32x4& o11, int ch) {
    float scc0 = 0.0f, scc1 = 0.0f;
    #pragma unroll
    for (int g = 0; g < 4; ++g) {
      float e00 = __builtin_amdgcn_exp2f(o00[g]);
      float e10 = __builtin_amdgcn_exp2f(o10[g]);
      float e01 = __builtin_amdgcn_exp2f(o01[g]);
      float e11 = __builtin_amdgcn_exp2f(o11[g]);
      se[0][g] += e00 + e01;
      se[1][g] += e10 + e11;
      scc0 += e00 + e10;
      scc1 += e01 + e11;
    }
    if (ch >= diag_until) {
      scc0 += __shfl_xor(scc0, 16, 64); scc0 += __shfl_xor(scc0, 32, 64);
      scc1 += __shfl_xor(scc1, 16, 64); scc1 += __shfl_xor(scc1, 32, 64);
      if (lane < 16) {
        atomicAdd(&colacc[ch * CH_COLS + lane], scc0);
        atomicAdd(&colacc[ch * CH_COLS + 16 + lane], scc1);
      }
    }
  };

  stage(0, 0);
  stage(1, 1);
  asm volatile("s_waitcnt vmcnt(4) lgkmcnt(0)" ::: "memory");  // chunk0 + zeros
  __builtin_amdgcn_s_barrier();

  f32x4 A00, A01, A10, A11, B00, B01, B10, B11;
  mfma_chunk(0, A00, A01, A10, A11);
  int ch = 0;
  while (true) {
    // A-half: accs A hold chunk ch
    if (ch + 2 < NT) stage((ch + 2) % 3, ch + 2);
    if (ch + 1 < NT) {
      if (ch + 2 < NT) asm volatile("s_waitcnt vmcnt(4)" ::: "memory");
      else             asm volatile("s_waitcnt vmcnt(0)" ::: "memory");
      __builtin_amdgcn_s_barrier();
      mfma_chunk(ch + 1, B00, B01, B10, B11);
      epilogue(A00, A01, A10, A11, ch);      // overlaps with B's MFMAs
    } else {
      epilogue(A00, A01, A10, A11, ch);
      break;
    }
    ++ch;
    // B-half: accs B hold chunk ch
    if (ch + 2 < NT) stage((ch + 2) % 3, ch + 2);
    if (ch + 1 < NT) {
      if (ch + 2 < NT) asm volatile("s_waitcnt vmcnt(4)" ::: "memory");
      else             asm volatile("s_waitcnt vmcnt(0)" ::: "memory");
      __builtin_amdgcn_s_barrier();
      mfma_chunk(ch + 1, A00, A01, A10, A11);
      epilogue(B00, B01, B10, B11, ch);
    } else {
      epilogue(B00, B01, B10, B11, ch);
      break;
    }
    ++ch;
  }

  __syncthreads();                            // colacc complete block-wide

  // row sums: reduce over 16 column-lanes, one atomic per row
  #pragma unroll
  for (int st = 0; st < 2; ++st) {
    #pragma unroll
    for (int g = 0; g < 4; ++g) {
      float v = se[st][g];
      #pragma unroll
      for (int m = 1; m <= 8; m <<= 1) v += __shfl_xor(v, m, 64);
      if (lrow == 0) atomicAdd(&rowsum[r0 + 16 * st + kgrp * 4 + g], v);
    }
  }

  // col sums flush: local col l -> global row (transposed tile)
  for (int l = threadIdx.x; l < NT * CH_COLS; l += 256) {
    int chn = l >> 5;
    if (chn >= diag_until) {
      int col = ((bi + dd0 + (chn >> 2)) & (NBLK - 1)) * ROWS_PER_BLOCK +
                (chn & 3) * CH_COLS + (l & 31);
      atomicAdd(&rowsum[col], colacc[l]);
    }
  }
}

// K3: per pair (i, j=i+N): subtract self term, lse - pos for both rows.
// Stored dots are KAPPA-scaled: pos = LN2*dp, self = exp2(sf - KAPPA).
__global__ __launch_bounds__(256) void k_rowred(const unsigned short* __restrict__ rnB,
                                               const float* __restrict__ rowsum,
                                               float* __restrict__ out) {
  __shared__ float ls[4];
  int wave = threadIdx.x >> 6, lane = threadIdx.x & 63;
  int q = lane & 31;
  float local = 0.0f;
  #pragma unroll
  for (int t = 0; t < 8; ++t) {
    int i = blockIdx.x * 32 + wave * 8 + t;              // pair 0..4095
    int row = (lane >> 5) ? i + HALF_N : i;
    int panel = row >> 4, r = row & 15;
    const char* addr = (const char*)rnB + (size_t)panel * PANEL_BYTES +
                       (q >> 2) * 1024 + ((q & 3) * 16 + r) * 16;
    ushort8 own = *reinterpret_cast<const ushort8*>(addr);
    int4 ow = *reinterpret_cast<int4*>(&own);
    int4 pw;
    pw.x = __shfl_xor(ow.x, 32, 64); pw.y = __shfl_xor(ow.y, 32, 64);
    pw.z = __shfl_xor(ow.z, 32, 64); pw.w = __shfl_xor(ow.w, 32, 64);
    ushort8 part = *reinterpret_cast<ushort8*>(&pw);
    float dp = 0.0f, sf = 0.0f;
    #pragma unroll
    for (int e = 0; e < 8; ++e) {
      float av = bf2f(own[e]), bv = bf2f(part[e]);
      dp += av * bv;
      sf += av * av;
    }
    #pragma unroll
    for (int m = 1; m <= 16; m <<= 1) {
      dp += __shfl_xor(dp, m, 64);
      sf += __shfl_xor(sf, m, 64);
    }
    if (q == 0) {                     // lanes 0 (row i) and 32 (row j)
      float self = __builtin_amdgcn_exp2f(sf - KAPPA);
      float rs = rowsum[row] - self;
      float lse = 10.0f + LN2 * __builtin_amdgcn_logf(rs);  // logf = log2
      local += lse - LN2 * dp;        // pos = 10*d = LN2 * (KAPPA*d)
    }
  }
  local += __shfl_xor(local, 32, 64);
  if (lane == 0) ls[wave] = local;
  __syncthreads();
  if (threadIdx.x == 0)
    atomicAdd(out, (ls[0] + ls[1] + ls[2] + ls[3]) * (1.0f / TWO_N));
}

extern "C" void kernel_launch(void* const* d_in, const int* in_sizes, int n_in,
                              void* d_out, int out_size, void* d_ws, size_t ws_size,
                              hipStream_t stream) {
  const float* zi = (const float*)d_in[0];
  const float* zj = (const float*)d_in[1];
  unsigned short* rnB = (unsigned short*)d_ws;                      // 4 MB
  float* rowsum = (float*)((char*)d_ws + (size_t)TWO_N * DIM * 2);  // 32 KB
  float* out = (float*)d_out;

  hipLaunchKernelGGL(k_norm, dim3(TWO_N / 16), dim3(256), 0, stream, zi, zj, rnB, rowsum, out);
  hipLaunchKernelGGL(k_sim, dim3(NBLK, 9), dim3(256), 0, stream, rnB, rowsum);
  hipLaunchKernelGGL(k_rowred, dim3(HALF_N / 32), dim3(256), 0, stream, rnB, rowsum, out);
}